// Round 11
// baseline (181.165 us; speedup 1.0000x reference)
//
#include <hip/hip_runtime.h>
#include <math.h>

#define NBOX 1024
#define PI_F 3.141592653f
#define TWO_PI_F 6.283185306f
#define HALF_PI_F 1.5707963265f
#define IOU_THR_F 0.3f

__device__ __forceinline__ float limit_period_f(float v) {
    return v - floorf(v / TWO_PI_F + 0.5f) * TWO_PI_F;
}

// ---------------------------------------------------------------------------
// Clip polygon (px,py,cnt) by half-plane left of edge (a->b).
// Fully unrolled, register-only (no runtime-indexed array writes).
// ---------------------------------------------------------------------------
__device__ __forceinline__ void clip_edge(float (&px)[8], float (&py)[8], int &cnt,
                                          float axp, float ayp, float bxp, float byp) {
    float ex = bxp - axp, ey = byp - ayp;
    float d[8];
#pragma unroll
    for (int v = 0; v < 8; ++v)
        d[v] = ex * (py[v] - ayp) - ey * (px[v] - axp);

    float cxv[16], cyv[16];
    bool fl[16];
#pragma unroll
    for (int v = 0; v < 8; ++v) {
        bool valid = v < cnt;
        bool wrap = !(v + 1 < cnt);              // reference: nxt = idx+1<cnt ? idx+1 : 0
        float p2x = wrap ? px[0] : px[(v + 1) & 7];
        float p2y = wrap ? py[0] : py[(v + 1) & 7];
        float d2v = wrap ? d[0] : d[(v + 1) & 7];
        float d1v = d[v];
        bool in1 = d1v >= 0.0f, in2 = d2v >= 0.0f;
        fl[2 * v] = in1 && valid;
        cxv[2 * v] = px[v];
        cyv[2 * v] = py[v];
        fl[2 * v + 1] = (in1 != in2) && valid;
        float den = d1v - d2v;
        float t = d1v / (fabsf(den) > 1e-8f ? den : 1.0f);
        cxv[2 * v + 1] = px[v] + t * (p2x - px[v]);
        cyv[2 * v + 1] = py[v] + t * (p2y - py[v]);
    }

    // Compact candidates into output slots with an unrolled select network.
    int pos = 0;
    float ox[8], oy[8];
#pragma unroll
    for (int o = 0; o < 8; ++o) { ox[o] = 0.0f; oy[o] = 0.0f; }
#pragma unroll
    for (int c = 0; c < 16; ++c) {
#pragma unroll
        for (int o = 0; o < 8; ++o) {
            if (o > c) continue;                 // pos[c] <= c, compile-time prune
            if (fl[c] && pos == o) { ox[o] = cxv[c]; oy[o] = cyv[c]; }
        }
        pos += fl[c] ? 1 : 0;
    }
    cnt = pos > 8 ? 8 : pos;
#pragma unroll
    for (int v = 0; v < 8; ++v) { px[v] = ox[v]; py[v] = oy[v]; }
}

// ---------------------------------------------------------------------------
// Kernel 1: pairwise IoU3D > 0.3 adjacency bitmask. One thread per (i,j);
// wave = 64 consecutive j for one i -> one u64 adjacency word per wave.
// Natural layout: adj[i*16 + g] bit l = adjacency(i, 64g + l).
// ---------------------------------------------------------------------------
__global__ __launch_bounds__(256) void iou_adj_kernel(const float* __restrict__ boxes,
                                                      unsigned long long* __restrict__ adj) {
    int t = blockIdx.x * 256 + threadIdx.x;
    int i = t >> 10;
    int j = t & 1023;
    const float* ba = boxes + i * 7;
    const float* bb = boxes + j * 7;
    float ax = ba[0], ay = ba[1], az = ba[2], al = ba[3], aw = ba[4], ah = ba[5];
    float bx = bb[0], by = bb[1], bz = bb[2], bl = bb[3], bw = bb[4], bh = bb[5];
    float tha = limit_period_f(ba[6]);
    float thb = limit_period_f(bb[6]);

    bool hit = false;
    float dx = ax - bx, dy = ay - by;
    float ra = 0.5f * sqrtf(al * al + aw * aw);
    float rb = 0.5f * sqrtf(bl * bl + bw * bw);
    float top = fminf(az + 0.5f * ah, bz + 0.5f * bh);
    float bot = fmaxf(az - 0.5f * ah, bz - 0.5f * bh);
    float hov = fmaxf(top - bot, 0.0f);
    float rr = ra + rb;
    // Exact reject: disjoint circumscribed circles or no height overlap => iou = 0.
    if (dx * dx + dy * dy <= rr * rr && hov > 0.0f) {
        float ca = cosf(tha), sa = sinf(tha);
        float cb = cosf(thb), sb = sinf(thb);

        float px[8], py[8];
        {   // corners of A: signs (0.5,-0.5),(0.5,0.5),(-0.5,0.5),(-0.5,-0.5)
            float hx = 0.5f * al, hy = 0.5f * aw;
            float sxv[4] = { hx, hx, -hx, -hx };
            float syv[4] = { -hy, hy, hy, -hy };
#pragma unroll
            for (int k = 0; k < 4; ++k) {
                px[k] = sxv[k] * ca - syv[k] * sa + ax;
                py[k] = sxv[k] * sa + syv[k] * ca + ay;
            }
#pragma unroll
            for (int k = 4; k < 8; ++k) { px[k] = 0.0f; py[k] = 0.0f; }
        }
        float qx[4], qy[4];
        {
            float hx = 0.5f * bl, hy = 0.5f * bw;
            float sxv[4] = { hx, hx, -hx, -hx };
            float syv[4] = { -hy, hy, hy, -hy };
#pragma unroll
            for (int k = 0; k < 4; ++k) {
                qx[k] = sxv[k] * cb - syv[k] * sb + bx;
                qy[k] = sxv[k] * sb + syv[k] * cb + by;
            }
        }
        int cnt = 4;
#pragma unroll
        for (int k = 0; k < 4; ++k)
            clip_edge(px, py, cnt, qx[k], qy[k], qx[(k + 1) & 3], qy[(k + 1) & 3]);

        // shoelace area over cnt vertices
        float s2 = 0.0f;
#pragma unroll
        for (int v = 0; v < 8; ++v) {
            bool valid = v < cnt;
            bool wrap = !(v + 1 < cnt);
            float p2x = wrap ? px[0] : px[(v + 1) & 7];
            float p2y = wrap ? py[0] : py[(v + 1) & 7];
            float cr = px[v] * p2y - p2x * py[v];
            s2 += valid ? cr : 0.0f;
        }
        float area = 0.5f * fabsf(s2);
        float inter = area * hov;
        float va = al * aw * ah, vb = bl * bw * bh;
        float iou = inter / fmaxf(va + vb - inter, 1e-6f);
        hit = iou > IOU_THR_F;
    }
    unsigned long long bal = __ballot(hit);
    if ((threadIdx.x & 63) == 0)
        adj[t >> 6] = bal;
}

// ---------------------------------------------------------------------------
// Kernel 2: greedy clustering, all from the NATURAL adjacency layout (the
// transpose kernel is gone). Box mapping: box b = 16*lane + g. Then the
// per-lane u16 #lane of natural row r (byte 2*lane of the 128B row) has
// bit g = adj(r, 16*lane+g): kills & assignment need NO transpose. Tile tau
// (rows 64tau..64tau+63) candidate mask c (u64 scalar) = 4 readlanes of um.
//
// Phase A (wave 0; serial chain ~ #seeds, not #rows): per tile, greedy
//   lexicographic MIS: while(c): s=ffs(c); c &= ~W_s via 2 readlanes of the
//   per-tile diagonal block (loaded per tile -> 2 VGPRs live, no spill risk
//   under launch_bounds(1024)'s 128-VGPR cap -- R3 lesson). Seed s also
//   issues ONE uniform-address LDS load of its kill-u16 (off the scalar
//   chain; consumed only at tile end): kill |= sA16[row(s)][lane]. Then
//   um &= ~kill; seq = cur + mbcnt-rank; cur += popcount(M).
//   Seed order == reference's strictly-increasing argmax(unassigned) scan.
// Phase B (16 waves): ci[b] = max over rows r of (adj(r,b) ? seq[r] : 0);
//   seq strictly increases => max == "last seed wins" == reference
//   reassignment semantics. Cross-wave max via 4KB part buffer.
// LDS: 128K (sA) + 4K (sseq) + 4K (part) = 136K <= 160K.
// ---------------------------------------------------------------------------
__global__ __launch_bounds__(1024) void cluster_kernel(const unsigned long long* __restrict__ adj,
                                                       int* __restrict__ ci,
                                                       int* __restrict__ nclust_out) {
    __shared__ unsigned long long sA[NBOX * 16];     // natural adjacency, 128 KiB
    __shared__ int sseq[NBOX];                       // 4 KiB
    __shared__ int part[16][64];                     // 4 KiB
    const unsigned short* sA16 = (const unsigned short*)sA;
    int tid = threadIdx.x;
#pragma unroll
    for (int j = 0; j < 16; ++j)
        sA[j * 1024 + tid] = adj[j * 1024 + tid];
    __syncthreads();

    int wid = tid >> 6;
    int lane = tid & 63;

    // ---- Phase A: per-tile greedy MIS on wave 0 ----
    if (wid == 0) {
        unsigned int um = 0xFFFFu;                   // bit g: box 16*lane+g unassigned
        int cur = 1;
        for (int t = 0; t < 16; ++t) {
            // Diagonal block of tile t: lane k holds row (64t+k)'s word t.
            unsigned long long dv = sA[(t * 64 + lane) * 16 + t];
            unsigned int dlo = (unsigned int)dv;
            unsigned int dhi = (unsigned int)(dv >> 32);
            // Candidate mask: boxes 64t..64t+63 = lanes 4t..4t+3 x 16 bits.
            unsigned long long c =
                ((unsigned long long)((unsigned int)__builtin_amdgcn_readlane((int)um, 4 * t)     & 0xFFFFu)) |
                ((unsigned long long)((unsigned int)__builtin_amdgcn_readlane((int)um, 4 * t + 1) & 0xFFFFu) << 16) |
                ((unsigned long long)((unsigned int)__builtin_amdgcn_readlane((int)um, 4 * t + 2) & 0xFFFFu) << 32) |
                ((unsigned long long)((unsigned int)__builtin_amdgcn_readlane((int)um, 4 * t + 3) & 0xFFFFu) << 48);
            unsigned long long M = 0ull;
            unsigned int kill = 0u;
            while (c) {
                int s = __ffsll((long long)c) - 1;   // uniform (SGPR)
                unsigned long long Ws =
                    ((unsigned long long)(unsigned int)__builtin_amdgcn_readlane((int)dhi, s) << 32) |
                    (unsigned long long)(unsigned int)__builtin_amdgcn_readlane((int)dlo, s);
                M |= (1ull << s);
                c &= ~Ws;                            // self-adjacency clears bit s too
                c &= ~(1ull << s);                   // safety
                kill |= (unsigned int)sA16[(t * 64 + s) * 64 + lane];   // off-chain load
            }
            um &= ~kill;
            // seq for this tile's rows: lane <-> row t*64+lane
            unsigned int mlo = (unsigned int)M, mhi = (unsigned int)(M >> 32);
            int rank = __builtin_amdgcn_mbcnt_hi(mhi, __builtin_amdgcn_mbcnt_lo(mlo, 0));
            int sd = (int)((M >> lane) & 1ull);
            sseq[t * 64 + lane] = sd ? (cur + rank) : 0;
            cur += __builtin_popcountll(M);
        }
        if (lane == 0)
            *nclust_out = cur - 1;
    }
    __syncthreads();

    // ---- Phase B: parallel assignment (max-reduction over rows) ----
    int cg[16];
#pragma unroll
    for (int g = 0; g < 16; ++g) cg[g] = 0;
    int rbase = wid * 64;
#pragma unroll 4
    for (int d = 0; d < 64; ++d) {
        int r = rbase + d;
        unsigned int x = sA16[r * 64 + lane];        // u16 #lane of row r (contig 128B/wave)
        int sq = sseq[r];                            // same-address broadcast
#pragma unroll
        for (int g = 0; g < 16; ++g) {
            bool h = ((x >> g) & 1u) != 0u;
            cg[g] = (h && sq > cg[g]) ? sq : cg[g];
        }
    }
#pragma unroll
    for (int g = 0; g < 16; ++g) {
        part[wid][lane] = cg[g];
        __syncthreads();
        if (wid == 0) {
            int m = part[0][lane];
#pragma unroll
            for (int w = 1; w < 16; ++w) m = m > part[w][lane] ? m : part[w][lane];
            ci[lane * 16 + g] = m;                   // box = 16*lane + g
        }
        __syncthreads();
    }
}

// ---------------------------------------------------------------------------
// Kernel 3: cluster fusion. Block = 256 threads = 4 waves; wave w handles
// cid = blockIdx*4 + w + 1. Boxes (heading limited), scores, ci in LDS.
// Block-level early exit when all 4 cids exceed n_clusters (block-uniform,
// skips the 36 KB LDS staging); per-wave early exit for empty cids otherwise.
// ---------------------------------------------------------------------------
__global__ __launch_bounds__(256) void fusion_kernel(const float* __restrict__ boxes,
                                                     const float* __restrict__ scores,
                                                     const int* __restrict__ ci,
                                                     const int* __restrict__ nclust_p,
                                                     float* __restrict__ out) {
    __shared__ float sb[NBOX][7];
    __shared__ float ss[NBOX];
    __shared__ int   sc[NBOX];
    int tid = threadIdx.x;
    int nclust = *nclust_p;                       // block-uniform scalar load

    if (blockIdx.x * 4 + 1 > nclust) {            // all 4 cids empty: zero rows, skip staging
        if (tid < 28) {
            out[blockIdx.x * 28 + tid] = 0.0f;    // 4 cids x 7 floats
        }
        return;
    }

    for (int idx = tid; idx < NBOX * 7; idx += 256) {
        float v = boxes[idx];
        int col = idx % 7;
        if (col == 6) v = limit_period_f(v);
        sb[idx / 7][col] = v;
    }
    for (int b = tid; b < NBOX; b += 256) {
        ss[b] = scores[b];
        sc[b] = ci[b];
    }
    __syncthreads();

    int wave = tid >> 6;
    int lane = tid & 63;
    int cid = blockIdx.x * 4 + wave + 1;

    // ---- pass 1: argmax of masked scores (first occurrence on ties) ----
    float bv = -INFINITY;
    int bi = 0;
    for (int c = 0; c < 16; ++c) {
        int b = c * 64 + lane;
        float v = (sc[b] == cid) ? ss[b] : -INFINITY;
        if (v > bv) { bv = v; bi = b; }          // ascending b => keeps first max
    }
#pragma unroll
    for (int off = 32; off > 0; off >>= 1) {
        float ov = __shfl_xor(bv, off);
        int   oi = __shfl_xor(bi, off);
        if (ov > bv || (ov == bv && oi < bi)) { bv = ov; bi = oi; }
    }
    float* o = out + (cid - 1) * 7;
    if (!(bv > -INFINITY)) {                     // empty cluster: all-zero row
        if (lane == 0) {
#pragma unroll
            for (int jj = 0; jj < 7; ++jj) o[jj] = 0.0f;
        }
        return;
    }
    float d0 = sb[bi][6];

    // ---- pass 2: flip decision + score sum ----
    float sgt = 0.0f, sngt = 0.0f, ssum = 0.0f;
    for (int c = 0; c < 16; ++c) {
        int b = c * 64 + lane;
        float s = (sc[b] == cid) ? ss[b] : 0.0f;
        float diff = fabsf(sb[b][6] - d0);
        diff = (diff > PI_F) ? (TWO_PI_F - diff) : diff;
        bool gt = diff > HALF_PI_F;
        sgt += gt ? s : 0.0f;
        sngt += gt ? 0.0f : s;
        ssum += s;
    }
#pragma unroll
    for (int off = 32; off > 0; off >>= 1) {
        sgt  += __shfl_xor(sgt, off);
        sngt += __shfl_xor(sngt, off);
        ssum += __shfl_xor(ssum, off);
    }
    bool flip = (sgt <= sngt);
    float inv = ssum;                            // non-empty => ssum > 0

    // ---- pass 3: weighted sums (sn applied per-box like the reference) ----
    float sint = 0.0f, cost = 0.0f;
    float acc[6] = { 0.0f, 0.0f, 0.0f, 0.0f, 0.0f, 0.0f };
    for (int c = 0; c < 16; ++c) {
        int b = c * 64 + lane;
        float s = (sc[b] == cid) ? ss[b] : 0.0f;
        float sn = s / inv;
        float dH = sb[b][6];
        float diff = fabsf(dH - d0);
        diff = (diff > PI_F) ? (TWO_PI_F - diff) : diff;
        bool gt = diff > HALF_PI_F;
        bool cond = flip ? gt : !gt;
        float dd = cond ? (dH + PI_F) : dH;
        dd = limit_period_f(dd);
        sint += sinf(dd) * sn;
        cost += cosf(dd) * sn;
#pragma unroll
        for (int jj = 0; jj < 6; ++jj)
            acc[jj] += sb[b][jj] * sn;
    }
#pragma unroll
    for (int off = 32; off > 0; off >>= 1) {
        sint += __shfl_xor(sint, off);
        cost += __shfl_xor(cost, off);
#pragma unroll
        for (int jj = 0; jj < 6; ++jj)
            acc[jj] += __shfl_xor(acc[jj], off);
    }

    if (lane == 0) {
#pragma unroll
        for (int jj = 0; jj < 6; ++jj) o[jj] = acc[jj];
        o[6] = atan2f(sint, cost);
    }
}

extern "C" void kernel_launch(void* const* d_in, const int* in_sizes, int n_in,
                              void* d_out, int out_size, void* d_ws, size_t ws_size,
                              hipStream_t stream) {
    const float* boxes  = (const float*)d_in[0];   // (1024,7) f32
    const float* scores = (const float*)d_in[1];   // (1024,)  f32
    // ws layout: [0,128K) natural adj (live: iou -> cluster staging); the
    // cluster kernel writes ci/nclust into the same region only AFTER its
    // last adj read (same block, program order) -- safe aliasing.
    unsigned long long* adj = (unsigned long long*)d_ws;
    int* ci     = (int*)d_ws;                          // 4 KiB, aliases dead adj
    int* nclust = (int*)((char*)d_ws + 4096);          // 4 B
    float* out = (float*)d_out;                        // (1024,7) f32

    iou_adj_kernel<<<(NBOX * NBOX) / 256, 256, 0, stream>>>(boxes, adj);
    cluster_kernel<<<1, 1024, 0, stream>>>(adj, ci, nclust);
    fusion_kernel<<<NBOX / 4, 256, 0, stream>>>(boxes, scores, ci, nclust, out);
}

// Round 12
// 160.761 us; speedup vs baseline: 1.1269x; 1.1269x over previous
//
#include <hip/hip_runtime.h>
#include <math.h>

#define NBOX 1024
#define PI_F 3.141592653f
#define TWO_PI_F 6.283185306f
#define HALF_PI_F 1.5707963265f
#define IOU_THR_F 0.3f

__device__ __forceinline__ float limit_period_f(float v) {
    return v - floorf(v / TWO_PI_F + 0.5f) * TWO_PI_F;
}

// ---------------------------------------------------------------------------
// Clip polygon (px,py,cnt) by half-plane left of edge (a->b).
// Fully unrolled, register-only (no runtime-indexed array writes).
// ---------------------------------------------------------------------------
__device__ __forceinline__ void clip_edge(float (&px)[8], float (&py)[8], int &cnt,
                                          float axp, float ayp, float bxp, float byp) {
    float ex = bxp - axp, ey = byp - ayp;
    float d[8];
#pragma unroll
    for (int v = 0; v < 8; ++v)
        d[v] = ex * (py[v] - ayp) - ey * (px[v] - axp);

    float cxv[16], cyv[16];
    bool fl[16];
#pragma unroll
    for (int v = 0; v < 8; ++v) {
        bool valid = v < cnt;
        bool wrap = !(v + 1 < cnt);              // reference: nxt = idx+1<cnt ? idx+1 : 0
        float p2x = wrap ? px[0] : px[(v + 1) & 7];
        float p2y = wrap ? py[0] : py[(v + 1) & 7];
        float d2v = wrap ? d[0] : d[(v + 1) & 7];
        float d1v = d[v];
        bool in1 = d1v >= 0.0f, in2 = d2v >= 0.0f;
        fl[2 * v] = in1 && valid;
        cxv[2 * v] = px[v];
        cyv[2 * v] = py[v];
        fl[2 * v + 1] = (in1 != in2) && valid;
        float den = d1v - d2v;
        float t = d1v / (fabsf(den) > 1e-8f ? den : 1.0f);
        cxv[2 * v + 1] = px[v] + t * (p2x - px[v]);
        cyv[2 * v + 1] = py[v] + t * (p2y - py[v]);
    }

    // Compact candidates into output slots with an unrolled select network.
    int pos = 0;
    float ox[8], oy[8];
#pragma unroll
    for (int o = 0; o < 8; ++o) { ox[o] = 0.0f; oy[o] = 0.0f; }
#pragma unroll
    for (int c = 0; c < 16; ++c) {
#pragma unroll
        for (int o = 0; o < 8; ++o) {
            if (o > c) continue;                 // pos[c] <= c, compile-time prune
            if (fl[c] && pos == o) { ox[o] = cxv[c]; oy[o] = cyv[c]; }
        }
        pos += fl[c] ? 1 : 0;
    }
    cnt = pos > 8 ? 8 : pos;
#pragma unroll
    for (int v = 0; v < 8; ++v) { px[v] = ox[v]; py[v] = oy[v]; }
}

// ---------------------------------------------------------------------------
// Kernel 1: pairwise IoU3D > 0.3 adjacency bitmask. One thread per (i,j);
// wave = 64 consecutive j for one i -> one u64 adjacency word per wave.
// Natural layout: adj[i*16 + g] bit l = adjacency(i, 64g + l).
// ---------------------------------------------------------------------------
__global__ __launch_bounds__(256) void iou_adj_kernel(const float* __restrict__ boxes,
                                                      unsigned long long* __restrict__ adj) {
    int t = blockIdx.x * 256 + threadIdx.x;
    int i = t >> 10;
    int j = t & 1023;
    const float* ba = boxes + i * 7;
    const float* bb = boxes + j * 7;
    float ax = ba[0], ay = ba[1], az = ba[2], al = ba[3], aw = ba[4], ah = ba[5];
    float bx = bb[0], by = bb[1], bz = bb[2], bl = bb[3], bw = bb[4], bh = bb[5];
    float tha = limit_period_f(ba[6]);
    float thb = limit_period_f(bb[6]);

    bool hit = false;
    float dx = ax - bx, dy = ay - by;
    float ra = 0.5f * sqrtf(al * al + aw * aw);
    float rb = 0.5f * sqrtf(bl * bl + bw * bw);
    float top = fminf(az + 0.5f * ah, bz + 0.5f * bh);
    float bot = fmaxf(az - 0.5f * ah, bz - 0.5f * bh);
    float hov = fmaxf(top - bot, 0.0f);
    float rr = ra + rb;
    // Exact reject: disjoint circumscribed circles or no height overlap => iou = 0.
    if (dx * dx + dy * dy <= rr * rr && hov > 0.0f) {
        float ca = cosf(tha), sa = sinf(tha);
        float cb = cosf(thb), sb = sinf(thb);

        float px[8], py[8];
        {   // corners of A: signs (0.5,-0.5),(0.5,0.5),(-0.5,0.5),(-0.5,-0.5)
            float hx = 0.5f * al, hy = 0.5f * aw;
            float sxv[4] = { hx, hx, -hx, -hx };
            float syv[4] = { -hy, hy, hy, -hy };
#pragma unroll
            for (int k = 0; k < 4; ++k) {
                px[k] = sxv[k] * ca - syv[k] * sa + ax;
                py[k] = sxv[k] * sa + syv[k] * ca + ay;
            }
#pragma unroll
            for (int k = 4; k < 8; ++k) { px[k] = 0.0f; py[k] = 0.0f; }
        }
        float qx[4], qy[4];
        {
            float hx = 0.5f * bl, hy = 0.5f * bw;
            float sxv[4] = { hx, hx, -hx, -hx };
            float syv[4] = { -hy, hy, hy, -hy };
#pragma unroll
            for (int k = 0; k < 4; ++k) {
                qx[k] = sxv[k] * cb - syv[k] * sb + bx;
                qy[k] = sxv[k] * sb + syv[k] * cb + by;
            }
        }
        int cnt = 4;
#pragma unroll
        for (int k = 0; k < 4; ++k)
            clip_edge(px, py, cnt, qx[k], qy[k], qx[(k + 1) & 3], qy[(k + 1) & 3]);

        // shoelace area over cnt vertices
        float s2 = 0.0f;
#pragma unroll
        for (int v = 0; v < 8; ++v) {
            bool valid = v < cnt;
            bool wrap = !(v + 1 < cnt);
            float p2x = wrap ? px[0] : px[(v + 1) & 7];
            float p2y = wrap ? py[0] : py[(v + 1) & 7];
            float cr = px[v] * p2y - p2x * py[v];
            s2 += valid ? cr : 0.0f;
        }
        float area = 0.5f * fabsf(s2);
        float inter = area * hov;
        float va = al * aw * ah, vb = bl * bw * bh;
        float iou = inter / fmaxf(va + vb - inter, 1e-6f);
        hit = iou > IOU_THR_F;
    }
    unsigned long long bal = __ballot(hit);
    if ((threadIdx.x & 63) == 0)
        adj[t >> 6] = bal;
}

// ---------------------------------------------------------------------------
// Kernel 2: greedy clustering from the NATURAL adjacency layout.
// Box mapping: box b = 16*lane + g (um bit g of lane b>>4).
//
// Phase A (wave 0): per 64-row tile, BRANCHLESS static-unrolled scan with the
// tile candidate mask c held in a SCALAR u64:
//   row k (static): W_k = 2x readlane(dlo/dhi, k) [static index, source VGPRs
//   stable -> compiler hoists them OFF the serial chain];
//   serial chain = pure SALU: sd=(c>>k)&1; msk=0-sd; M|=msk&(1<<k);
//   c&=~(msk&W_k).  Cross-tile kill is an off-chain VALU accumulator:
//   kill |= sd ? tb[k] : 0 (tb = static LDS preloads), consumed once at tile
//   end (um &= ~kill). Seq numbering via M + mbcnt rank (R11 pattern).
//   R11 lesson: while-loop branches + dynamic-index readlanes cost ~230
//   cyc/seed; this body is ~5 SALU/row with no branches at all.
//   Seed order == reference's strictly-increasing argmax(unassigned) scan;
//   seed set == greedy lexicographic MIS.
// Phase B (16 waves): ci[b] = max over rows r of (adj(r,b) ? seq[r] : 0)
//   (seq strictly increases => max == "last seed wins" == reference
//   reassignment). Cross-wave combine via LDS atomicMax (1 barrier instead
//   of R11's 32).
// LDS: 128K (sA) + 4K (sseq) + 4K (cimax) = 136K <= 160K.
// ---------------------------------------------------------------------------
__global__ __launch_bounds__(1024) void cluster_kernel(const unsigned long long* __restrict__ adj,
                                                       int* __restrict__ ci,
                                                       int* __restrict__ nclust_out) {
    __shared__ unsigned long long sA[NBOX * 16];     // natural adjacency, 128 KiB
    __shared__ int sseq[NBOX];                       // 4 KiB
    __shared__ int cimax[NBOX];                      // 4 KiB
    const unsigned short* sA16 = (const unsigned short*)sA;
    int tid = threadIdx.x;
#pragma unroll
    for (int j = 0; j < 16; ++j)
        sA[j * 1024 + tid] = adj[j * 1024 + tid];
    cimax[tid] = 0;
    __syncthreads();

    int wid = tid >> 6;
    int lane = tid & 63;

    // ---- Phase A: branchless per-tile scan on wave 0 ----
    if (wid == 0) {
        unsigned int um = 0xFFFFu;                   // bit g: box 16*lane+g unassigned
        int cur = 1;
        for (int t = 0; t < 16; ++t) {
            // Diagonal block of tile t: lane k holds row (64t+k)'s word t.
            unsigned long long dv = sA[(t * 64 + lane) * 16 + t];
            unsigned int dlo = (unsigned int)dv;
            unsigned int dhi = (unsigned int)(dv >> 32);
            // Kill u16s for this tile's rows (static addrs -> SROA, off-chain).
            unsigned short tb[64];
#pragma unroll
            for (int k = 0; k < 64; ++k)
                tb[k] = sA16[(t * 64 + k) * 64 + lane];
            // Candidate mask (scalar): boxes 64t..64t+63 = lanes 4t..4t+3 x 16b.
            unsigned long long c =
                ((unsigned long long)((unsigned int)__builtin_amdgcn_readlane((int)um, 4 * t)     & 0xFFFFu)) |
                ((unsigned long long)((unsigned int)__builtin_amdgcn_readlane((int)um, 4 * t + 1) & 0xFFFFu) << 16) |
                ((unsigned long long)((unsigned int)__builtin_amdgcn_readlane((int)um, 4 * t + 2) & 0xFFFFu) << 32) |
                ((unsigned long long)((unsigned int)__builtin_amdgcn_readlane((int)um, 4 * t + 3) & 0xFFFFu) << 48);
            unsigned long long M = 0ull;
            unsigned int kill = 0u;
#pragma unroll
            for (int k = 0; k < 64; ++k) {
                unsigned int wl = (unsigned int)__builtin_amdgcn_readlane((int)dlo, k); // static idx
                unsigned int wh = (unsigned int)__builtin_amdgcn_readlane((int)dhi, k); // static idx
                unsigned long long W = ((unsigned long long)wh << 32) | (unsigned long long)wl;
                unsigned long long sd = (c >> k) & 1ull;            // scalar
                unsigned long long msk = 0ull - sd;                 // scalar 0/~0
                M |= msk & (1ull << k);
                c &= ~(msk & W);                                    // self-adj clears bit k
                kill |= ((unsigned int)(0u - (unsigned int)sd)) & (unsigned int)tb[k]; // off-chain VALU
            }
            um &= ~kill;
            // seq for this tile's rows: lane <-> row t*64+lane
            unsigned int mlo = (unsigned int)M, mhi = (unsigned int)(M >> 32);
            int rank = __builtin_amdgcn_mbcnt_hi(mhi, __builtin_amdgcn_mbcnt_lo(mlo, 0));
            int sd2 = (int)((M >> lane) & 1ull);
            sseq[t * 64 + lane] = sd2 ? (cur + rank) : 0;
            cur += __builtin_popcountll(M);
        }
        if (lane == 0)
            *nclust_out = cur - 1;
    }
    __syncthreads();

    // ---- Phase B: parallel assignment (max-reduction over rows) ----
    int cg[16];
#pragma unroll
    for (int g = 0; g < 16; ++g) cg[g] = 0;
    int rbase = wid * 64;
#pragma unroll 4
    for (int d = 0; d < 64; ++d) {
        int r = rbase + d;
        unsigned int x = sA16[r * 64 + lane];        // u16 #lane of row r (contig 128B/wave)
        int sq = sseq[r];                            // same-address broadcast
#pragma unroll
        for (int g = 0; g < 16; ++g) {
            bool h = ((x >> g) & 1u) != 0u;
            cg[g] = (h && sq > cg[g]) ? sq : cg[g];
        }
    }
#pragma unroll
    for (int g = 0; g < 16; ++g)
        atomicMax(&cimax[lane * 16 + g], cg[g]);     // box = 16*lane + g
    __syncthreads();
    ci[tid] = cimax[tid];
}

// ---------------------------------------------------------------------------
// Kernel 3: cluster fusion. Block = 256 threads = 4 waves; wave w handles
// cid = blockIdx*4 + w + 1. Boxes (heading limited), scores, ci in LDS.
// Block-level early exit when all 4 cids exceed n_clusters (block-uniform,
// skips the 36 KB LDS staging); per-wave early exit for empty cids otherwise.
// ---------------------------------------------------------------------------
__global__ __launch_bounds__(256) void fusion_kernel(const float* __restrict__ boxes,
                                                     const float* __restrict__ scores,
                                                     const int* __restrict__ ci,
                                                     const int* __restrict__ nclust_p,
                                                     float* __restrict__ out) {
    __shared__ float sb[NBOX][7];
    __shared__ float ss[NBOX];
    __shared__ int   sc[NBOX];
    int tid = threadIdx.x;
    int nclust = *nclust_p;                       // block-uniform scalar load

    if (blockIdx.x * 4 + 1 > nclust) {            // all 4 cids empty: zero rows, skip staging
        if (tid < 28) {
            out[blockIdx.x * 28 + tid] = 0.0f;    // 4 cids x 7 floats
        }
        return;
    }

    for (int idx = tid; idx < NBOX * 7; idx += 256) {
        float v = boxes[idx];
        int col = idx % 7;
        if (col == 6) v = limit_period_f(v);
        sb[idx / 7][col] = v;
    }
    for (int b = tid; b < NBOX; b += 256) {
        ss[b] = scores[b];
        sc[b] = ci[b];
    }
    __syncthreads();

    int wave = tid >> 6;
    int lane = tid & 63;
    int cid = blockIdx.x * 4 + wave + 1;

    // ---- pass 1: argmax of masked scores (first occurrence on ties) ----
    float bv = -INFINITY;
    int bi = 0;
    for (int c = 0; c < 16; ++c) {
        int b = c * 64 + lane;
        float v = (sc[b] == cid) ? ss[b] : -INFINITY;
        if (v > bv) { bv = v; bi = b; }          // ascending b => keeps first max
    }
#pragma unroll
    for (int off = 32; off > 0; off >>= 1) {
        float ov = __shfl_xor(bv, off);
        int   oi = __shfl_xor(bi, off);
        if (ov > bv || (ov == bv && oi < bi)) { bv = ov; bi = oi; }
    }
    float* o = out + (cid - 1) * 7;
    if (!(bv > -INFINITY)) {                     // empty cluster: all-zero row
        if (lane == 0) {
#pragma unroll
            for (int jj = 0; jj < 7; ++jj) o[jj] = 0.0f;
        }
        return;
    }
    float d0 = sb[bi][6];

    // ---- pass 2: flip decision + score sum ----
    float sgt = 0.0f, sngt = 0.0f, ssum = 0.0f;
    for (int c = 0; c < 16; ++c) {
        int b = c * 64 + lane;
        float s = (sc[b] == cid) ? ss[b] : 0.0f;
        float diff = fabsf(sb[b][6] - d0);
        diff = (diff > PI_F) ? (TWO_PI_F - diff) : diff;
        bool gt = diff > HALF_PI_F;
        sgt += gt ? s : 0.0f;
        sngt += gt ? 0.0f : s;
        ssum += s;
    }
#pragma unroll
    for (int off = 32; off > 0; off >>= 1) {
        sgt  += __shfl_xor(sgt, off);
        sngt += __shfl_xor(sngt, off);
        ssum += __shfl_xor(ssum, off);
    }
    bool flip = (sgt <= sngt);
    float inv = ssum;                            // non-empty => ssum > 0

    // ---- pass 3: weighted sums (sn applied per-box like the reference) ----
    float sint = 0.0f, cost = 0.0f;
    float acc[6] = { 0.0f, 0.0f, 0.0f, 0.0f, 0.0f, 0.0f };
    for (int c = 0; c < 16; ++c) {
        int b = c * 64 + lane;
        float s = (sc[b] == cid) ? ss[b] : 0.0f;
        float sn = s / inv;
        float dH = sb[b][6];
        float diff = fabsf(dH - d0);
        diff = (diff > PI_F) ? (TWO_PI_F - diff) : diff;
        bool gt = diff > HALF_PI_F;
        bool cond = flip ? gt : !gt;
        float dd = cond ? (dH + PI_F) : dH;
        dd = limit_period_f(dd);
        sint += sinf(dd) * sn;
        cost += cosf(dd) * sn;
#pragma unroll
        for (int jj = 0; jj < 6; ++jj)
            acc[jj] += sb[b][jj] * sn;
    }
#pragma unroll
    for (int off = 32; off > 0; off >>= 1) {
        sint += __shfl_xor(sint, off);
        cost += __shfl_xor(cost, off);
#pragma unroll
        for (int jj = 0; jj < 6; ++jj)
            acc[jj] += __shfl_xor(acc[jj], off);
    }

    if (lane == 0) {
#pragma unroll
        for (int jj = 0; jj < 6; ++jj) o[jj] = acc[jj];
        o[6] = atan2f(sint, cost);
    }
}

extern "C" void kernel_launch(void* const* d_in, const int* in_sizes, int n_in,
                              void* d_out, int out_size, void* d_ws, size_t ws_size,
                              hipStream_t stream) {
    const float* boxes  = (const float*)d_in[0];   // (1024,7) f32
    const float* scores = (const float*)d_in[1];   // (1024,)  f32
    // ws layout: [0,128K) natural adj (live: iou -> cluster staging); the
    // cluster kernel writes ci/nclust into the same region only AFTER its
    // last adj read (same block, program order) -- safe aliasing.
    unsigned long long* adj = (unsigned long long*)d_ws;
    int* ci     = (int*)d_ws;                          // 4 KiB, aliases dead adj
    int* nclust = (int*)((char*)d_ws + 4096);          // 4 B
    float* out = (float*)d_out;                        // (1024,7) f32

    iou_adj_kernel<<<(NBOX * NBOX) / 256, 256, 0, stream>>>(boxes, adj);
    cluster_kernel<<<1, 1024, 0, stream>>>(adj, ci, nclust);
    fusion_kernel<<<NBOX / 4, 256, 0, stream>>>(boxes, scores, ci, nclust, out);
}